// Round 1
// baseline (578.319 us; speedup 1.0000x reference)
//
#include <hip/hip_runtime.h>

// Problem constants (B=2, S=2048, HID=2048, H=16, D=128)
#define S_LEN   2048
#define HEADS   16
#define HID_DIM 2048
#define HEAD_D  128
#define BATCH   2

typedef __bf16          bf16x8 __attribute__((ext_vector_type(8)));
typedef unsigned short  u16x8  __attribute__((ext_vector_type(8)));
typedef float           f32x4  __attribute__((ext_vector_type(4)));

__device__ __forceinline__ unsigned short f2bf(float f) {
  unsigned u = __builtin_bit_cast(unsigned, f);
  u += 0x7FFFu + ((u >> 16) & 1u);          // round-to-nearest-even
  return (unsigned short)(u >> 16);
}
__device__ __forceinline__ float bf2f(unsigned short s) {
  unsigned u = ((unsigned)s) << 16;
  return __builtin_bit_cast(float, u);
}

__device__ __forceinline__ f32x4 mfma16(u16x8 a, u16x8 b, f32x4 c) {
  return __builtin_amdgcn_mfma_f32_16x16x32_bf16(
      __builtin_bit_cast(bf16x8, a), __builtin_bit_cast(bf16x8, b), c, 0, 0, 0);
}

__device__ __forceinline__ void async_load16(const void* g, void* l) {
  __builtin_amdgcn_global_load_lds(
      (const __attribute__((address_space(1))) void*)g,
      (__attribute__((address_space(3))) void*)l, 16, 0, 0);
}

// ---------------- f32 -> bf16 convert (vectorized) ----------------
__global__ __launch_bounds__(256) void cvt_bf16(const float* __restrict__ in,
                                                unsigned short* __restrict__ out,
                                                int n8) {
  for (int i = blockIdx.x * blockDim.x + threadIdx.x; i < n8;
       i += gridDim.x * blockDim.x) {
    const float4* p = (const float4*)in + 2L * i;
    float4 a = p[0], b = p[1];
    u16x8 v;
    v[0] = f2bf(a.x); v[1] = f2bf(a.y); v[2] = f2bf(a.z); v[3] = f2bf(a.w);
    v[4] = f2bf(b.x); v[5] = f2bf(b.y); v[6] = f2bf(b.z); v[7] = f2bf(b.w);
    ((u16x8*)out)[i] = v;
  }
}

// ------------- W (K x N f32) -> Wt (N x K bf16) transpose ----------
__global__ __launch_bounds__(256) void transpose_cvt(const float* __restrict__ W,
                                                     unsigned short* __restrict__ Wt,
                                                     int dim) {
  __shared__ float tile[32][33];
  const int bx = blockIdx.x * 32, by = blockIdx.y * 32;
  const int tx = threadIdx.x, ty = threadIdx.y;   // 32 x 8
#pragma unroll
  for (int i = 0; i < 32; i += 8)
    tile[ty + i][tx] = W[(long)(by + ty + i) * dim + bx + tx];
  __syncthreads();
#pragma unroll
  for (int i = 0; i < 32; i += 8)
    Wt[(long)(bx + ty + i) * dim + by + tx] = f2bf(tile[tx][ty + i]);
}

// ---------------- RoPE on Q and K (in-place, bf16) -----------------
__global__ __launch_bounds__(256) void rope_qk(unsigned short* __restrict__ Qb,
                                               unsigned short* __restrict__ Kb,
                                               const float* __restrict__ fcos,
                                               const float* __restrict__ fsin) {
  const long i = (long)blockIdx.x * blockDim.x + threadIdx.x; // < B*S*H*64
  const int d = (int)(i & 63);
  const int h = (int)((i >> 6) & (HEADS - 1));
  const long row = i >> 10;                 // b*S + s
  const int s = (int)(row & (S_LEN - 1));
  const long base = row * HID_DIM + h * HEAD_D + d;
  const float c0 = fcos[s * HEAD_D + d], c1 = fcos[s * HEAD_D + d + 64];
  const float s0 = fsin[s * HEAD_D + d], s1 = fsin[s * HEAD_D + d + 64];
  const float q0 = bf2f(Qb[base]), q1 = bf2f(Qb[base + 64]);
  Qb[base]      = f2bf(q0 * c0 - q1 * s0);
  Qb[base + 64] = f2bf(q1 * c1 + q0 * s1);
  const float k0 = bf2f(Kb[base]), k1 = bf2f(Kb[base + 64]);
  Kb[base]      = f2bf(k0 * c0 - k1 * s0);
  Kb[base + 64] = f2bf(k1 * c1 + k0 * s1);
}

// ------- GEMM: C(MxN) = A(MxK,bf16) @ Bt(NxK,bf16)^T  (m97 shape) ---
__global__ __launch_bounds__(256) void gemm_bt(const unsigned short* __restrict__ A,
                                               const unsigned short* __restrict__ Bt,
                                               unsigned short* __restrict__ Cb,
                                               float* __restrict__ Cf,
                                               int M, int N, int K) {
  __shared__ __align__(16) unsigned short Alds[128 * 32];
  __shared__ __align__(16) unsigned short Blds[128 * 32];
  const int t = threadIdx.x;
  const int lane = t & 63;
  const int w = t >> 6;
  const int wr = w >> 1, wc = w & 1;
  const int l15 = lane & 15, l4 = lane >> 4;
  const int bx = blockIdx.x, by = blockIdx.y;

  f32x4 acc[4][4] = {};

  const long rowA = (long)by * 128 + (t >> 2);
  const long rowB = (long)bx * 128 + (t >> 2);
  const int kcol = (t & 3) * 8;
  char* aDst0 = (char*)Alds + t * 16;
  char* aDst1 = (char*)Alds + 4096 + t * 16;
  char* bDst0 = (char*)Blds + t * 16;
  char* bDst1 = (char*)Blds + 4096 + t * 16;
  const unsigned short* aSrc = A + rowA * K + kcol;
  const unsigned short* bSrc = Bt + rowB * K + kcol;
  const long skip = 64L * K;

  const int aBase = (wr * 64 + l15) * 32 + l4 * 8;
  const int bBase = (wc * 64 + l15) * 32 + l4 * 8;

  for (int kt = 0; kt < K; kt += 32) {
    __syncthreads();                       // previous tile's reads done
    async_load16(aSrc + kt, aDst0);
    async_load16(aSrc + kt + skip, aDst1);
    async_load16(bSrc + kt, bDst0);
    async_load16(bSrc + kt + skip, bDst1);
    __syncthreads();                       // staging visible (vmcnt drained)
    u16x8 af[4], bfv[4];
#pragma unroll
    for (int m = 0; m < 4; ++m) af[m] = *(const u16x8*)&Alds[aBase + m * 512];
#pragma unroll
    for (int n = 0; n < 4; ++n) bfv[n] = *(const u16x8*)&Blds[bBase + n * 512];
#pragma unroll
    for (int m = 0; m < 4; ++m)
#pragma unroll
      for (int n = 0; n < 4; ++n)
        acc[m][n] = mfma16(af[m], bfv[n], acc[m][n]);
  }

  const long orow = (long)by * 128 + wr * 64 + l4 * 4;
  const long ocol = (long)bx * 128 + wc * 64 + l15;
#pragma unroll
  for (int m = 0; m < 4; ++m)
#pragma unroll
    for (int n = 0; n < 4; ++n)
#pragma unroll
      for (int r = 0; r < 4; ++r) {
        const long row = orow + m * 16 + r;
        const long col = ocol + n * 16;
        if (Cb) Cb[row * N + col] = f2bf(acc[m][n][r]);
        else    Cf[row * N + col] = acc[m][n][r];
      }
}

// --------------- fused causal+alibi flash attention ----------------
// grid: (S/64, H, B); block: 256 (4 waves, 16 q-rows each)
__global__ __launch_bounds__(256) void attn_fwd(const unsigned short* __restrict__ Q,
                                                const unsigned short* __restrict__ K,
                                                const unsigned short* __restrict__ V,
                                                const float* __restrict__ alibi,
                                                unsigned short* __restrict__ O) {
  __shared__ __align__(16) unsigned short Vt[128][40];   // padded: V transposed
  __shared__ __align__(16) unsigned short P[4][16][40];  // per-wave P tile
  const int t = threadIdx.x;
  const int lane = t & 63;
  const int w = t >> 6;
  const int l15 = lane & 15, l4 = lane >> 4;
  const int qb = blockIdx.x * 64;
  const int h = blockIdx.y;
  const int b = blockIdx.z;
  const long base = ((long)b * S_LEN) * HID_DIM + h * HEAD_D;
  const float nslope = alibi[h * S_LEN + 1];   // = -slope_h (alibi at k=1)
  const float scale = 0.08838834764831845f;    // 1/sqrt(128)

  u16x8 qf[4];
  {
    const int qrow = qb + w * 16 + l15;
    const unsigned short* qp = Q + base + (long)qrow * HID_DIM + l4 * 8;
#pragma unroll
    for (int dc = 0; dc < 4; ++dc) qf[dc] = *(const u16x8*)(qp + dc * 32);
  }

  f32x4 acc[8] = {};
  float m_r[4], l_r[4];
#pragma unroll
  for (int r = 0; r < 4; ++r) { m_r[r] = -1e30f; l_r[r] = 0.f; }

  const int vkr = t & 31;          // V stage: row in k-tile
  const int vc0 = (t >> 5) * 16;   // V stage: col base
  const int ktmax = qb / 32 + 2;   // causal bound

  for (int kt = 0; kt < ktmax; ++kt) {
    const int kb = kt * 32;
    __syncthreads();               // LDS reusable
    { // stage V tile transposed into Vt[d][k]
      const unsigned short* vsrc = V + base + (long)(kb + vkr) * HID_DIM + vc0;
      u16x8 v0 = *(const u16x8*)vsrc;
      u16x8 v1 = *(const u16x8*)(vsrc + 8);
#pragma unroll
      for (int j = 0; j < 8; ++j) Vt[vc0 + j][vkr] = v0[j];
#pragma unroll
      for (int j = 0; j < 8; ++j) Vt[vc0 + 8 + j][vkr] = v1[j];
    }
    // QK^T: S tile 16x32 per wave (two 16x16 MFMA outputs, K-dim=128)
    f32x4 sacc[2] = {};
#pragma unroll
    for (int n = 0; n < 2; ++n) {
      const unsigned short* kp =
          K + base + (long)(kb + n * 16 + l15) * HID_DIM + l4 * 8;
#pragma unroll
      for (int dc = 0; dc < 4; ++dc) {
        u16x8 kf = *(const u16x8*)(kp + dc * 32);
        sacc[n] = mfma16(qf[dc], kf, sacc[n]);
      }
    }
    // scale + alibi + causal mask, online softmax (wave-parallel reduce)
    const int qg0 = qb + w * 16 + l4 * 4;
    float sv[2][4], rmax[4];
#pragma unroll
    for (int r = 0; r < 4; ++r) {
#pragma unroll
      for (int n = 0; n < 2; ++n) {
        const int kg = kb + n * 16 + l15;
        float v = sacc[n][r] * scale + nslope * (float)kg;
        if (kg > qg0 + r) v -= 1e9f;
        sv[n][r] = v;
      }
      rmax[r] = fmaxf(sv[0][r], sv[1][r]);
    }
#pragma unroll
    for (int off = 1; off < 16; off <<= 1)
#pragma unroll
      for (int r = 0; r < 4; ++r)
        rmax[r] = fmaxf(rmax[r], __shfl_xor(rmax[r], off, 64));
    float sf[4];
#pragma unroll
    for (int r = 0; r < 4; ++r) {
      const float mn = fmaxf(m_r[r], rmax[r]);
      sf[r] = __expf(m_r[r] - mn);
      m_r[r] = mn;
    }
    float p0[4], p1[4], rsum[4];
#pragma unroll
    for (int r = 0; r < 4; ++r) {
      p0[r] = __expf(sv[0][r] - m_r[r]);
      p1[r] = __expf(sv[1][r] - m_r[r]);
      rsum[r] = p0[r] + p1[r];
    }
#pragma unroll
    for (int off = 1; off < 16; off <<= 1)
#pragma unroll
      for (int r = 0; r < 4; ++r) rsum[r] += __shfl_xor(rsum[r], off, 64);
#pragma unroll
    for (int r = 0; r < 4; ++r) l_r[r] = l_r[r] * sf[r] + rsum[r];
#pragma unroll
    for (int dt = 0; dt < 8; ++dt)
#pragma unroll
      for (int r = 0; r < 4; ++r) acc[dt][r] *= sf[r];
    // write P (C-layout -> LDS) for A-fragment consumption
#pragma unroll
    for (int r = 0; r < 4; ++r) {
      P[w][l4 * 4 + r][l15]      = f2bf(p0[r]);
      P[w][l4 * 4 + r][16 + l15] = f2bf(p1[r]);
    }
    __syncthreads();               // Vt + P visible
    // PV: out(16x128) += P(16x32) @ V(32x128)
    u16x8 pa = *(const u16x8*)&P[w][l15][l4 * 8];
#pragma unroll
    for (int dt = 0; dt < 8; ++dt) {
      u16x8 vb = *(const u16x8*)&Vt[dt * 16 + l15][l4 * 8];
      acc[dt] = mfma16(pa, vb, acc[dt]);
    }
  }
  // epilogue: normalize and store bf16 (B*S, HID) layout
#pragma unroll
  for (int r = 0; r < 4; ++r) {
    const float inv = 1.0f / l_r[r];
    const long orow = base + (long)(qb + w * 16 + l4 * 4 + r) * HID_DIM;
#pragma unroll
    for (int dt = 0; dt < 8; ++dt)
      O[orow + dt * 16 + l15] = f2bf(acc[dt][r] * inv);
  }
}

extern "C" void kernel_launch(void* const* d_in, const int* in_sizes, int n_in,
                              void* d_out, int out_size, void* d_ws, size_t ws_size,
                              hipStream_t stream) {
  const float* x    = (const float*)d_in[0];
  const float* Wq   = (const float*)d_in[1];
  const float* Wk   = (const float*)d_in[2];
  const float* Wv   = (const float*)d_in[3];
  const float* Wo   = (const float*)d_in[4];
  // d_in[5] = attention_mask (causal, reproduced analytically)
  const float* alibi = (const float*)d_in[6];
  const float* fcos  = (const float*)d_in[7];
  const float* fsin  = (const float*)d_in[8];

  char* ws = (char*)d_ws;
  // layout (bytes): xb/AO 0..16M | wt0 16..24M | wt1 24..32M | wt2 32..40M
  //                 Q 40..56M | K 56..72M | V 72..88M      (needs 88 MiB)
  unsigned short* xb  = (unsigned short*)(ws);
  unsigned short* wt0 = (unsigned short*)(ws + (16L << 20));
  unsigned short* wt1 = (unsigned short*)(ws + (24L << 20));
  unsigned short* wt2 = (unsigned short*)(ws + (32L << 20));
  unsigned short* Qb  = (unsigned short*)(ws + (40L << 20));
  unsigned short* Kb  = (unsigned short*)(ws + (56L << 20));
  unsigned short* Vb  = (unsigned short*)(ws + (72L << 20));

  const int M = BATCH * S_LEN;   // 4096
  const int N = HID_DIM;         // 2048
  const int K = HID_DIM;         // 2048

  cvt_bf16<<<2048, 256, 0, stream>>>(x, xb, M * K / 8);

  dim3 tb(32, 8), tg(N / 32, K / 32);
  transpose_cvt<<<tg, tb, 0, stream>>>(Wq, wt0, N);
  transpose_cvt<<<tg, tb, 0, stream>>>(Wk, wt1, N);
  transpose_cvt<<<tg, tb, 0, stream>>>(Wv, wt2, N);

  dim3 gg(N / 128, M / 128);
  gemm_bt<<<gg, 256, 0, stream>>>(xb, wt0, Qb, nullptr, M, N, K);
  gemm_bt<<<gg, 256, 0, stream>>>(xb, wt1, Kb, nullptr, M, N, K);
  gemm_bt<<<gg, 256, 0, stream>>>(xb, wt2, Vb, nullptr, M, N, K);

  rope_qk<<<(BATCH * S_LEN * HEADS * 64) / 256, 256, 0, stream>>>(Qb, Kb, fcos, fsin);

  transpose_cvt<<<tg, tb, 0, stream>>>(Wo, wt0, N);  // reuse wt0 after QKV GEMMs

  attn_fwd<<<dim3(S_LEN / 64, HEADS, BATCH), 256, 0, stream>>>(Qb, Kb, Vb, alibi, xb);

  gemm_bt<<<gg, 256, 0, stream>>>(xb, wt0, nullptr, (float*)d_out, M, N, K);
}

// Round 2
// 518.780 us; speedup vs baseline: 1.1148x; 1.1148x over previous
//
#include <hip/hip_runtime.h>

// Problem constants (B=2, S=2048, HID=2048, H=16, D=128)
#define S_LEN   2048
#define HEADS   16
#define HID_DIM 2048
#define HEAD_D  128
#define BATCH   2

typedef __bf16          bf16x8 __attribute__((ext_vector_type(8)));
typedef unsigned short  u16x8  __attribute__((ext_vector_type(8)));
typedef unsigned short  u16x4  __attribute__((ext_vector_type(4)));
typedef float           f32x4  __attribute__((ext_vector_type(4)));

__device__ __forceinline__ unsigned short f2bf(float f) {
  unsigned u = __builtin_bit_cast(unsigned, f);
  u += 0x7FFFu + ((u >> 16) & 1u);          // round-to-nearest-even
  return (unsigned short)(u >> 16);
}
__device__ __forceinline__ float bf2f(unsigned short s) {
  unsigned u = ((unsigned)s) << 16;
  return __builtin_bit_cast(float, u);
}

__device__ __forceinline__ f32x4 mfma16(u16x8 a, u16x8 b, f32x4 c) {
  return __builtin_amdgcn_mfma_f32_16x16x32_bf16(
      __builtin_bit_cast(bf16x8, a), __builtin_bit_cast(bf16x8, b), c, 0, 0, 0);
}

__device__ __forceinline__ void async_load16(const void* g, void* l) {
  __builtin_amdgcn_global_load_lds(
      (const __attribute__((address_space(1))) void*)g,
      (__attribute__((address_space(3))) void*)l, 16, 0, 0);
}

// ---------------- f32 -> bf16 convert (vectorized) ----------------
__global__ __launch_bounds__(256) void cvt_bf16(const float* __restrict__ in,
                                                unsigned short* __restrict__ out,
                                                int n8) {
  for (int i = blockIdx.x * blockDim.x + threadIdx.x; i < n8;
       i += gridDim.x * blockDim.x) {
    const float4* p = (const float4*)in + 2L * i;
    float4 a = p[0], b = p[1];
    u16x8 v;
    v[0] = f2bf(a.x); v[1] = f2bf(a.y); v[2] = f2bf(a.z); v[3] = f2bf(a.w);
    v[4] = f2bf(b.x); v[5] = f2bf(b.y); v[6] = f2bf(b.z); v[7] = f2bf(b.w);
    ((u16x8*)out)[i] = v;
  }
}

// ------------- W (K x N f32) -> Wt (N x K bf16) transpose ----------
__global__ __launch_bounds__(256) void transpose_cvt(const float* __restrict__ W,
                                                     unsigned short* __restrict__ Wt,
                                                     int dim) {
  __shared__ float tile[32][33];
  const int bx = blockIdx.x * 32, by = blockIdx.y * 32;
  const int tx = threadIdx.x, ty = threadIdx.y;   // 32 x 8
#pragma unroll
  for (int i = 0; i < 32; i += 8)
    tile[ty + i][tx] = W[(long)(by + ty + i) * dim + bx + tx];
  __syncthreads();
#pragma unroll
  for (int i = 0; i < 32; i += 8)
    Wt[(long)(bx + ty + i) * dim + by + tx] = f2bf(tile[tx][ty + i]);
}

// ---- V (B*S x HID bf16) -> Vt (bh x D x S bf16) head-transpose ----
__global__ __launch_bounds__(256) void transpose_v(const unsigned short* __restrict__ V,
                                                   unsigned short* __restrict__ Vt) {
  __shared__ unsigned short tile[32][34];
  const int s0 = blockIdx.x * 32, d0 = blockIdx.y * 32, bh = blockIdx.z;
  const int b = bh >> 4, h = bh & 15;
  const int tx = threadIdx.x, ty = threadIdx.y;   // 32 x 8
#pragma unroll
  for (int i = 0; i < 32; i += 8)
    tile[ty + i][tx] =
        V[(long)(b * S_LEN + s0 + ty + i) * HID_DIM + h * HEAD_D + d0 + tx];
  __syncthreads();
#pragma unroll
  for (int i = 0; i < 32; i += 8)
    Vt[((long)bh * HEAD_D + d0 + ty + i) * S_LEN + s0 + tx] = tile[tx][ty + i];
}

// ---------------- RoPE on Q and K (in-place, bf16) -----------------
__global__ __launch_bounds__(256) void rope_qk(unsigned short* __restrict__ Qb,
                                               unsigned short* __restrict__ Kb,
                                               const float* __restrict__ fcos,
                                               const float* __restrict__ fsin) {
  const long i = (long)blockIdx.x * blockDim.x + threadIdx.x; // < B*S*H*64
  const int d = (int)(i & 63);
  const int h = (int)((i >> 6) & (HEADS - 1));
  const long row = i >> 10;                 // b*S + s
  const int s = (int)(row & (S_LEN - 1));
  const long base = row * HID_DIM + h * HEAD_D + d;
  const float c0 = fcos[s * HEAD_D + d], c1 = fcos[s * HEAD_D + d + 64];
  const float s0 = fsin[s * HEAD_D + d], s1 = fsin[s * HEAD_D + d + 64];
  const float q0 = bf2f(Qb[base]), q1 = bf2f(Qb[base + 64]);
  Qb[base]      = f2bf(q0 * c0 - q1 * s0);
  Qb[base + 64] = f2bf(q1 * c1 + q0 * s1);
  const float k0 = bf2f(Kb[base]), k1 = bf2f(Kb[base + 64]);
  Kb[base]      = f2bf(k0 * c0 - k1 * s0);
  Kb[base + 64] = f2bf(k1 * c1 + k0 * s1);
}

// ------- GEMM: C(MxN) = A(MxK,bf16) @ Bt(NxK,bf16)^T  (m97 shape) ---
__global__ __launch_bounds__(256) void gemm_bt(const unsigned short* __restrict__ A,
                                               const unsigned short* __restrict__ Bt,
                                               unsigned short* __restrict__ Cb,
                                               float* __restrict__ Cf,
                                               int M, int N, int K) {
  __shared__ __align__(16) unsigned short Alds[128 * 32];
  __shared__ __align__(16) unsigned short Blds[128 * 32];
  const int t = threadIdx.x;
  const int lane = t & 63;
  const int w = t >> 6;
  const int wr = w >> 1, wc = w & 1;
  const int l15 = lane & 15, l4 = lane >> 4;
  const int bx = blockIdx.x, by = blockIdx.y;

  f32x4 acc[4][4] = {};

  const long rowA = (long)by * 128 + (t >> 2);
  const long rowB = (long)bx * 128 + (t >> 2);
  const int kcol = (t & 3) * 8;
  char* aDst0 = (char*)Alds + t * 16;
  char* aDst1 = (char*)Alds + 4096 + t * 16;
  char* bDst0 = (char*)Blds + t * 16;
  char* bDst1 = (char*)Blds + 4096 + t * 16;
  const unsigned short* aSrc = A + rowA * K + kcol;
  const unsigned short* bSrc = Bt + rowB * K + kcol;
  const long skip = 64L * K;

  const int aBase = (wr * 64 + l15) * 32 + l4 * 8;
  const int bBase = (wc * 64 + l15) * 32 + l4 * 8;

  for (int kt = 0; kt < K; kt += 32) {
    __syncthreads();                       // previous tile's reads done
    async_load16(aSrc + kt, aDst0);
    async_load16(aSrc + kt + skip, aDst1);
    async_load16(bSrc + kt, bDst0);
    async_load16(bSrc + kt + skip, bDst1);
    __syncthreads();                       // staging visible (vmcnt drained)
    u16x8 af[4], bfv[4];
#pragma unroll
    for (int m = 0; m < 4; ++m) af[m] = *(const u16x8*)&Alds[aBase + m * 512];
#pragma unroll
    for (int n = 0; n < 4; ++n) bfv[n] = *(const u16x8*)&Blds[bBase + n * 512];
#pragma unroll
    for (int m = 0; m < 4; ++m)
#pragma unroll
      for (int n = 0; n < 4; ++n)
        acc[m][n] = mfma16(af[m], bfv[n], acc[m][n]);
  }

  const long orow = (long)by * 128 + wr * 64 + l4 * 4;
  const long ocol = (long)bx * 128 + wc * 64 + l15;
#pragma unroll
  for (int m = 0; m < 4; ++m)
#pragma unroll
    for (int n = 0; n < 4; ++n)
#pragma unroll
      for (int r = 0; r < 4; ++r) {
        const long row = orow + m * 16 + r;
        const long col = ocol + n * 16;
        if (Cb) Cb[row * N + col] = f2bf(acc[m][n][r]);
        else    Cf[row * N + col] = acc[m][n][r];
      }
}

// --------------- fused causal+alibi flash attention v2 -------------
// Swapped QK^T (S^T in-lane softmax), V pre-transposed (B-frags straight
// from global/L2), barrier-free; per-wave 32 q-rows, 64-key tiles.
// grid: 512 blocks x 256 thr; waves independent.
__global__ __launch_bounds__(256) void attn_fwd2(const unsigned short* __restrict__ Q,
                                                 const unsigned short* __restrict__ K,
                                                 const unsigned short* __restrict__ Vt,
                                                 const float* __restrict__ alibi,
                                                 unsigned short* __restrict__ O) {
  __shared__ __align__(16) unsigned short Pl[4][32][72];  // per-wave P tile
  const int t = threadIdx.x;
  const int lane = t & 63;
  const int w = t >> 6;
  const int l15 = lane & 15, l4 = lane >> 4;
  const int bx = blockIdx.x;
  const int bh = bx >> 4;              // 0..31 : (b,h)
  const int i16 = bx & 15;             // 0..15 : q-tile pair index
  const int h = bh & (HEADS - 1), b = bh >> 4;
  const int qt = (w < 2) ? (i16 * 2 + w) : (63 - i16 * 2 - (w - 2));
  const int q0 = qt * 32;
  const float nslope = alibi[h * S_LEN + 1];   // = -slope_h
  const float scale = 0.08838834764831845f;    // 1/sqrt(128)

  const long rowbase = ((long)b * S_LEN) * HID_DIM + h * HEAD_D; // Q,K,O
  const long vtbase  = ((long)bh * HEAD_D) * S_LEN;              // Vt

  // Q fragments (used as MFMA B operand): row=q at l15, d contiguous
  u16x8 qf[2][4];
  {
    const unsigned short* qp = Q + rowbase + (long)(q0 + l15) * HID_DIM + l4 * 8;
#pragma unroll
    for (int m = 0; m < 2; ++m)
#pragma unroll
      for (int ds = 0; ds < 4; ++ds)
        qf[m][ds] = *(const u16x8*)(qp + (long)m * 16 * HID_DIM + ds * 32);
  }

  f32x4 acc[2][8] = {};
  float m_r[2] = {-1e30f, -1e30f};
  float l_r[2] = {0.f, 0.f};

  const unsigned short* kp0 = K + rowbase + (long)l15 * HID_DIM + l4 * 8;
  const unsigned short* vp0 = Vt + vtbase + (long)l15 * S_LEN + l4 * 8;

  const int nkt = (q0 >> 6) + 1;
  for (int kt = 0; kt < nkt; ++kt) {
    const int kb = kt * 64;
    // ---- QK^T swapped: S^T[k][q] tiles (4 k-frags x 2 q-frags) ----
    f32x4 sacc[4][2] = {};
#pragma unroll
    for (int ds = 0; ds < 4; ++ds) {
      u16x8 kfr[4];
#pragma unroll
      for (int n = 0; n < 4; ++n)
        kfr[n] = *(const u16x8*)(kp0 + (long)(kb + 16 * n) * HID_DIM + ds * 32);
#pragma unroll
      for (int n = 0; n < 4; ++n)
#pragma unroll
        for (int m = 0; m < 2; ++m)
          sacc[n][m] = mfma16(kfr[n], qf[m][ds], sacc[n][m]);
    }
    // ---- online softmax, in-lane over k (lane's q-col = l15) ----
#pragma unroll
    for (int m = 0; m < 2; ++m) {
      const int q = q0 + 16 * m + l15;
      float pv[4][4];
      float rmax = -1e30f;
#pragma unroll
      for (int n = 0; n < 4; ++n)
#pragma unroll
        for (int r = 0; r < 4; ++r) {
          const int k = kb + 16 * n + l4 * 4 + r;
          float v = sacc[n][m][r] * scale + nslope * (float)k;
          if (k > q) v = -1e30f;
          pv[n][r] = v;
          rmax = fmaxf(rmax, v);
        }
      rmax = fmaxf(rmax, __shfl_xor(rmax, 16, 64));
      rmax = fmaxf(rmax, __shfl_xor(rmax, 32, 64));
      const float mnew = fmaxf(m_r[m], rmax);
      const float sf = __expf(m_r[m] - mnew);
      m_r[m] = mnew;
      float rsum = 0.f;
#pragma unroll
      for (int n = 0; n < 4; ++n)
#pragma unroll
        for (int r = 0; r < 4; ++r) {
          pv[n][r] = __expf(pv[n][r] - mnew);
          rsum += pv[n][r];
        }
      rsum += __shfl_xor(rsum, 16, 64);
      rsum += __shfl_xor(rsum, 32, 64);
      l_r[m] = l_r[m] * sf + rsum;
      // redistribute sf (per l15=q) to O C-layout rows (q = l4*4+r)
      float sfo[4];
#pragma unroll
      for (int r = 0; r < 4; ++r) sfo[r] = __shfl(sf, l4 * 4 + r, 64);
#pragma unroll
      for (int dt = 0; dt < 8; ++dt)
#pragma unroll
        for (int r = 0; r < 4; ++r) acc[m][dt][r] *= sfo[r];
      // store P^T (lane holds 4 consecutive k per n-frag) -> b64 writes
#pragma unroll
      for (int n = 0; n < 4; ++n) {
        u16x4 pk;
#pragma unroll
        for (int r = 0; r < 4; ++r) pk[r] = f2bf(pv[n][r]);
        *(u16x4*)&Pl[w][16 * m + l15][16 * n + l4 * 4] = pk;
      }
    }
    // ---- PV: A = P from LDS (b128), B = Vt straight from global ----
    u16x8 pf[2][2];
#pragma unroll
    for (int m = 0; m < 2; ++m)
#pragma unroll
      for (int kf = 0; kf < 2; ++kf)
        pf[m][kf] = *(const u16x8*)&Pl[w][16 * m + l15][kf * 32 + l4 * 8];
#pragma unroll
    for (int kf = 0; kf < 2; ++kf)
#pragma unroll
      for (int dt = 0; dt < 8; ++dt) {
        u16x8 vb = *(const u16x8*)(vp0 + (long)dt * 16 * S_LEN + kb + kf * 32);
#pragma unroll
        for (int m = 0; m < 2; ++m)
          acc[m][dt] = mfma16(pf[m][kf], vb, acc[m][dt]);
      }
  }
  // ---- epilogue: normalize, store bf16 (B*S, HID) ----
#pragma unroll
  for (int m = 0; m < 2; ++m) {
    float linv[4];
#pragma unroll
    for (int r = 0; r < 4; ++r)
      linv[r] = 1.0f / __shfl(l_r[m], l4 * 4 + r, 64);
#pragma unroll
    for (int dt = 0; dt < 8; ++dt)
#pragma unroll
      for (int r = 0; r < 4; ++r) {
        const long row = q0 + 16 * m + l4 * 4 + r;
        O[rowbase + row * HID_DIM + dt * 16 + l15] = f2bf(acc[m][dt][r] * linv[r]);
      }
  }
}

extern "C" void kernel_launch(void* const* d_in, const int* in_sizes, int n_in,
                              void* d_out, int out_size, void* d_ws, size_t ws_size,
                              hipStream_t stream) {
  const float* x    = (const float*)d_in[0];
  const float* Wq   = (const float*)d_in[1];
  const float* Wk   = (const float*)d_in[2];
  const float* Wv   = (const float*)d_in[3];
  const float* Wo   = (const float*)d_in[4];
  // d_in[5] = attention_mask (causal, reproduced analytically)
  const float* alibi = (const float*)d_in[6];
  const float* fcos  = (const float*)d_in[7];
  const float* fsin  = (const float*)d_in[8];

  char* ws = (char*)d_ws;
  // layout (bytes): xb/AO 0..16M | wt0 16..24M | Vt 24..40M (reuses wt1+wt2)
  //                 Q 40..56M | K 56..72M | V 72..88M      (needs 88 MiB)
  unsigned short* xb  = (unsigned short*)(ws);
  unsigned short* wt0 = (unsigned short*)(ws + (16L << 20));
  unsigned short* wt1 = (unsigned short*)(ws + (24L << 20));
  unsigned short* wt2 = (unsigned short*)(ws + (32L << 20));
  unsigned short* VtG = (unsigned short*)(ws + (24L << 20));  // after K/V gemms
  unsigned short* Qb  = (unsigned short*)(ws + (40L << 20));
  unsigned short* Kb  = (unsigned short*)(ws + (56L << 20));
  unsigned short* Vb  = (unsigned short*)(ws + (72L << 20));

  const int M = BATCH * S_LEN;   // 4096
  const int N = HID_DIM;         // 2048
  const int K = HID_DIM;         // 2048

  cvt_bf16<<<2048, 256, 0, stream>>>(x, xb, M * K / 8);

  dim3 tb(32, 8), tg(N / 32, K / 32);
  transpose_cvt<<<tg, tb, 0, stream>>>(Wq, wt0, N);
  transpose_cvt<<<tg, tb, 0, stream>>>(Wk, wt1, N);
  transpose_cvt<<<tg, tb, 0, stream>>>(Wv, wt2, N);

  dim3 gg(N / 128, M / 128);
  gemm_bt<<<gg, 256, 0, stream>>>(xb, wt0, Qb, nullptr, M, N, K);
  gemm_bt<<<gg, 256, 0, stream>>>(xb, wt1, Kb, nullptr, M, N, K);
  gemm_bt<<<gg, 256, 0, stream>>>(xb, wt2, Vb, nullptr, M, N, K);

  rope_qk<<<(BATCH * S_LEN * HEADS * 64) / 256, 256, 0, stream>>>(Qb, Kb, fcos, fsin);

  // head-transpose V -> Vt[bh][d][s]   (overwrites wt1/wt2, both dead now)
  transpose_v<<<dim3(S_LEN / 32, HEAD_D / 32, BATCH * HEADS), tb, 0, stream>>>(Vb, VtG);

  transpose_cvt<<<tg, tb, 0, stream>>>(Wo, wt0, N);  // reuse wt0

  attn_fwd2<<<512, 256, 0, stream>>>(Qb, Kb, VtG, alibi, xb);

  gemm_bt<<<gg, 256, 0, stream>>>(xb, wt0, nullptr, (float*)d_out, M, N, K);
}